// Round 11
// baseline (107.074 us; speedup 1.0000x reference)
//
#include <hip/hip_runtime.h>

// Deformable conv (K=3, stride=1, pad=1, dil=1), N=8, Cin=Cout=128, H=W=64.
// v12: v11 (reg-stash fusion, 102.7us total) runs at 1 block/CU (256-VGPR budget) so
//   phase A (gather latency chain) and phase B (9 barrier-coupled MFMA taps) are
//   strictly serial with nothing else on the CU. Fix: halve the block footprint so
//   TWO blocks co-reside and overlap phases ACROSS blocks:
//   - grid 1024: n = bid&7 (XCD-local), ho = (bid>>3)&63, ph = bid>>9 (wo half).
//   - 512 thr: thread samples 8 ch/tap (stash[9][4] = 36 VGPR, gv 16) for pos
//     lp = t>>4 (32 pos/block), cb = (t&15)*8.
//   - phase B: 8 waves, wave = 32 pos x 16 co (2 mt x 1 nt x 4 ct = 8 MFMA/tap),
//     verified wt2 B-frag path, dbuf LDS samp[2][32][SROW] = 17.4KB.
//   - __launch_bounds__(512,4): 128-VGPR cap -> 2 resident blocks/CU (16 waves,
//     4/SIMD), 4 queued. Known cost: B re-read doubles (295MB L2 aggregate, ~8.5us
//     floor, pipelined).
//   - keeps: XCD-local n, cvt_pk_bf16, padded SROW, verified MFMA/wt2 layouts,
//     barrier-free phase A, reg stash (no S buffer).
// ws: xt 8MB @0; wt2 288KB @8388608. Fully rewritten each launch.

#define H  64
#define W  64
#define CIN 128
#define COUT 128
#define NB 8
#define KK 9
#define SROW (CIN + 8)

typedef short bf16x8 __attribute__((ext_vector_type(8)));
typedef float f32x4  __attribute__((ext_vector_type(4)));

__device__ __forceinline__ unsigned short f2bf(float f) {
    unsigned u = __builtin_bit_cast(unsigned, f);
    u += 0x7FFFu + ((u >> 16) & 1u);          // round-nearest-even
    return (unsigned short)(u >> 16);
}
__device__ __forceinline__ unsigned cvt_pk_bf16(float lo, float hi) {
    unsigned r;
    asm("v_cvt_pk_bf16_f32 %0, %1, %2" : "=v"(r) : "v"(lo), "v"(hi));
    return r;                                  // low16 = bf16(lo), high16 = bf16(hi), RNE
}
__device__ __forceinline__ float lo_f(unsigned u) { return __builtin_bit_cast(float, u << 16); }
__device__ __forceinline__ float hi_f(unsigned u) { return __builtin_bit_cast(float, u & 0xFFFF0000u); }

// Merged prep: blocks [0, NB*H) transpose x (NCHW fp32 -> NHWC bf16), XCD-local (n = b&7);
// blocks [NB*H, NB*H+576): weight fp32 [co][c][kk] -> wt2 fragment-contiguous bf16:
//   wt2 flat idx = ((((kk*4 + c4)*2 + nt)*4 + ct)*64 + lm*4 + lq)*8 + e
//   where co = c4*32 + nt*16 + lm, ch = ct*32 + lq*8 + e.   [verified rounds 6-10]
__global__ void prep_all(const float* __restrict__ x, const float* __restrict__ w,
                         unsigned short* __restrict__ xt, unsigned short* __restrict__ wt) {
    int b = blockIdx.x;
    int t = threadIdx.x;
    if (b >= NB * H) {                        // ---- weight part ----
        int idx = (b - NB * H) * 256 + t;
        if (idx < KK * COUT * CIN) {
            int e  = idx & 7;
            int lq = (idx >> 3) & 3;
            int lm = (idx >> 5) & 15;
            int ct = (idx >> 9) & 3;
            int nt = (idx >> 11) & 1;
            int c4 = (idx >> 12) & 3;
            int kk = idx >> 14;
            int co = (c4 << 5) + (nt << 4) + lm;
            int ch = (ct << 5) + (lq << 3) + e;
            wt[idx] = f2bf(w[(co * CIN + ch) * KK + kk]);
        }
        return;
    }
    // ---- x-transpose part: one (n,y) row per block; n = b&7 matches XCD map ----
    __shared__ float tile[CIN][W + 4];
    int n = b & 7, y = b >> 3;
    const float* src = x + ((size_t)n * CIN * H + y) * W;
    #pragma unroll
    for (int it = 0; it < 8; ++it) {
        int idx = it * 256 + t;               // 0..2047 float4s
        int c  = idx >> 4;
        int x4 = (idx & 15) << 2;
        int xs = (x4 + ((c >> 5) << 4)) & 63; // rotate-swizzle per 32-ch group
        *(float4*)&tile[c][xs] = *(const float4*)(src + (size_t)c * H * W + x4);
    }
    __syncthreads();
    int xp = t >> 2;                          // x position 0..63
    int cbch = (t & 3) << 5;                  // channel base (32-ch chunk)
    int xr = (xp + ((cbch >> 5) << 4)) & 63;
    unsigned short* dst = xt + (((size_t)(n * H + y) * W + xp) * CIN + cbch);
    unsigned rr[16];
    #pragma unroll
    for (int i = 0; i < 16; ++i)
        rr[i] = cvt_pk_bf16(tile[cbch + 2 * i][xr], tile[cbch + 2 * i + 1][xr]);
    #pragma unroll
    for (int i = 0; i < 4; ++i)
        ((uint4*)dst)[i] = make_uint4(rr[4*i], rr[4*i+1], rr[4*i+2], rr[4*i+3]);
}

struct GatherCtx {
    const unsigned short *c00, *c01, *c10, *c11;
    float w00, w01, w10, w11;
};

__device__ __forceinline__ GatherCtx gather_setup(float dy, float dx, int ho, int wo, int kk,
                                                  const unsigned short* xbase) {
    GatherCtx g;
    float py = (float)(ho - 1 + kk / 3) + dy;
    float px = (float)(wo - 1 + kk % 3) + dx;
    float y0f = floorf(py), x0f = floorf(px);
    float wy1 = py - y0f, wx1 = px - x0f;
    float wy0 = 1.f - wy1, wx0 = 1.f - wx1;
    int y0 = (int)y0f, x0 = (int)x0f;
    int y1 = y0 + 1, x1 = x0 + 1;
    bool vy0 = (unsigned)y0 < (unsigned)H, vy1 = (unsigned)y1 < (unsigned)H;
    bool vx0 = (unsigned)x0 < (unsigned)W, vx1 = (unsigned)x1 < (unsigned)W;
    g.w00 = (vy0 && vx0) ? wy0 * wx0 : 0.f;
    g.w01 = (vy0 && vx1) ? wy0 * wx1 : 0.f;
    g.w10 = (vy1 && vx0) ? wy1 * wx0 : 0.f;
    g.w11 = (vy1 && vx1) ? wy1 * wx1 : 0.f;
    int yc0 = min(max(y0, 0), H - 1), yc1 = min(max(y1, 0), H - 1);
    int xc0 = min(max(x0, 0), W - 1), xc1 = min(max(x1, 0), W - 1);
    const unsigned short* r0 = xbase + (size_t)yc0 * W * CIN;
    const unsigned short* r1 = xbase + (size_t)yc1 * W * CIN;
    g.c00 = r0 + xc0 * CIN;  g.c01 = r0 + xc1 * CIN;
    g.c10 = r1 + xc0 * CIN;  g.c11 = r1 + xc1 * CIN;
    return g;
}

// Fused kernel: one block per (n, ho, wo-half); n = bid&7 (XCD-local). 512 thr = 8 waves.
__global__ __launch_bounds__(512, 4) void fused_main(
        const float* __restrict__ offs, const unsigned short* __restrict__ xt,
        const unsigned short* __restrict__ wt, float* __restrict__ out) {
    __shared__ __attribute__((aligned(16))) unsigned short samp[2][32][SROW];  // 17,408 B

    int b = blockIdx.x;
    int n = b & 7, ho = (b >> 3) & 63, ph = b >> 9;
    int t = threadIdx.x;
    int lane = t & 63, wv = t >> 6;
    int lm = lane & 15, lq = lane >> 4;

    // sampling map: local pos lp = t>>4 (0..31), 8-ch chunk cb = (t&15)*8
    int lp = t >> 4;
    int cb = (t & 15) << 3;
    int wo = (ph << 5) + lp;

    // ---------------- phase A: sample all 9 taps -> stash (regs; no barriers) --------
    const float* offp = offs + (size_t)n * 2 * KK * H * W + (size_t)ho * W + wo;
    const unsigned short* xb = xt + (size_t)n * H * W * CIN + cb;

    unsigned stash[KK][4];                    // 36 VGPR, statically indexed (rule #20)
    #pragma unroll
    for (int tap = 0; tap < KK; ++tap) {
        float dy = offp[(size_t)(2 * tap) * H * W];
        float dx = offp[(size_t)(2 * tap + 1) * H * W];
        GatherCtx g = gather_setup(dy, dx, ho, wo, tap, xb);
        uint4 q00 = *(const uint4*)(g.c00);
        uint4 q01 = *(const uint4*)(g.c01);
        uint4 q10 = *(const uint4*)(g.c10);
        uint4 q11 = *(const uint4*)(g.c11);
        const unsigned* a0 = (const unsigned*)&q00;
        const unsigned* a1 = (const unsigned*)&q01;
        const unsigned* a2 = (const unsigned*)&q10;
        const unsigned* a3 = (const unsigned*)&q11;
        #pragma unroll
        for (int i = 0; i < 4; ++i) {
            float v0 = g.w00*lo_f(a0[i]) + g.w01*lo_f(a1[i]) + g.w10*lo_f(a2[i]) + g.w11*lo_f(a3[i]);
            float v1 = g.w00*hi_f(a0[i]) + g.w01*hi_f(a1[i]) + g.w10*hi_f(a2[i]) + g.w11*hi_f(a3[i]);
            stash[tap][i] = cvt_pk_bf16(v0, v1);
        }
    }

    // ---------------- phase B: GEMM over taps (8 waves, wave = 32 pos x 16 co) --------
    f32x4 acc[2];
    acc[0] = f32x4{0.f, 0.f, 0.f, 0.f};
    acc[1] = f32x4{0.f, 0.f, 0.f, 0.f};

    int slot = (lm << 2) + lq;
    // wave wv covers co block wv*16: wt2 base (tap*8 + wv)*2048 + slot*8; frag ct at +ct*512
    const unsigned short* wvbase = wt + ((size_t)wv << 11) + (slot << 3);

    // prologue: stage tap 0 from regs (one 16B ds_write per thread)
    *(uint4*)&samp[0][lp][cb] = make_uint4(stash[0][0], stash[0][1], stash[0][2], stash[0][3]);
    __syncthreads();

    #pragma unroll
    for (int tap = 0; tap < KK; ++tap) {
        if (tap < KK - 1)                     // stage tap+1 into the other buffer
            *(uint4*)&samp[(tap + 1) & 1][lp][cb] =
                make_uint4(stash[tap+1][0], stash[tap+1][1], stash[tap+1][2], stash[tap+1][3]);

        // B-frags for this tap (verified wt2 layout), 4 x b128 per wave-lane
        const unsigned short* wkb = wvbase + ((size_t)tap << 14);
        bf16x8 bW[4];
        #pragma unroll
        for (int ct = 0; ct < 4; ++ct)
            bW[ct] = *(const bf16x8*)(wkb + (ct << 9));

        __builtin_amdgcn_s_setprio(1);
        #pragma unroll
        for (int ct = 0; ct < 4; ++ct) {
            bf16x8 a0 = *(const bf16x8*)&samp[tap & 1][lm]     [(ct << 5) + (lq << 3)];
            bf16x8 a1 = *(const bf16x8*)&samp[tap & 1][lm + 16][(ct << 5) + (lq << 3)];
            acc[0] = __builtin_amdgcn_mfma_f32_16x16x32_bf16(a0, bW[ct], acc[0], 0, 0, 0);
            acc[1] = __builtin_amdgcn_mfma_f32_16x16x32_bf16(a1, bW[ct], acc[1], 0, 0, 0);
        }
        __builtin_amdgcn_s_setprio(0);
        __syncthreads();
    }

    // epilogue: D[m = mt*16 + lq*4 + j][col = lm] -> out[n][co][ho][wo], float4 over wo
    int co = (wv << 4) + lm;
    #pragma unroll
    for (int mt = 0; mt < 2; ++mt) {
        int wob = (ph << 5) + (mt << 4) + (lq << 2);
        *(f32x4*)(out + (((size_t)(n * COUT + co) * H + ho) * W + wob)) = acc[mt];
    }
}

extern "C" void kernel_launch(void* const* d_in, const int* in_sizes, int n_in,
                              void* d_out, int out_size, void* d_ws, size_t ws_size,
                              hipStream_t stream) {
    const float* x      = (const float*)d_in[0];   // (8,128,64,64)
    const float* offset = (const float*)d_in[1];   // (8,18,64,64)
    const float* weight = (const float*)d_in[2];   // (128,128,3,3)
    float* out = (float*)d_out;

    unsigned short* xt = (unsigned short*)d_ws;                                  // 8 MB
    unsigned short* wt = (unsigned short*)((char*)d_ws + 8388608);               // 288 KB

    int wblocks = (KK * COUT * CIN + 255) / 256;   // 576
    hipLaunchKernelGGL(prep_all, dim3(NB * H + wblocks), dim3(256), 0, stream,
                       x, weight, xt, wt);
    hipLaunchKernelGGL(fused_main, dim3(NB * H * 2), dim3(512), 0, stream,
                       offset, xt, wt, out);
}